// Round 6
// baseline (213.093 us; speedup 1.0000x reference)
//
#include <hip/hip_runtime.h>

// BatchDelayProcessor: out[b,t] = x[b,t]*(1-MIX) + delayed[b,t]*MIX
//   delayed[t<D] = 0 ; delayed[t] = x[t-D] + FB*delayed[t-D]
// => per (b, i) column, a 20-step serial scan over blocks of D samples.
//
// R1: depth-2 prefetch -> 70us @ 2.44 TB/s (31% peak).
// R2-R5: three MLP attempts (load-all, sched_barrier, asm liveness fence)
//   ALL null even when VGPR rose 20->32. Little's law: ~8192 resident waves
//   x depth-2 x 512B = 8.4MB in flight -- plenty. Kernel is THROUGHPUT-
//   capped ~3.2 TB/s CU-side, not latency-starved. MLP hypothesis dead.
// R6: attack the throughput cap itself:
//   (a) 2 adjacent float2 columns per thread -> 1KB contiguous per wave
//       per k-block (vs 512B) -> better DRAM row locality for the ~40
//       interleaved streams.
//   (b) grid 2757 -> 1379 blocks (<= 2048 resident slots) -> single
//       residency round, no low-occupancy tail round.
//   (c) nontemporal loads+stores: output doesn't allocate in L2/L3, so
//       the L3-warm input stays resident (FETCH was already only half of
//       the 113MB input; should drop further).

typedef float f2 __attribute__((ext_vector_type(2)));

constexpr int   kB    = 64;
constexpr int   kT    = 441000;
constexpr int   kD    = 22050;          // delay in samples
constexpr int   kNBLK = kT / kD;        // 20 blocks
constexpr float kFB   = 0.3f;
constexpr float kMIX  = 0.5f;

constexpr int kHALF  = kD / 2;          // 11025 float2 columns per block
constexpr int kCOLS  = kB * kHALF;      // 705600 float2 columns total
constexpr int kPAIRS = kCOLS / 2;       // 352800 threads (2 columns each)

__global__ __launch_bounds__(256)
void delay_scan_kernel(const float* __restrict__ x, float* __restrict__ out) {
    int t = blockIdx.x * blockDim.x + threadIdx.x;
    if (t >= kPAIRS) return;

    // Two ADJACENT float2 columns -> 16B contiguous per thread per k-block,
    // 1KB contiguous per wave per k-block.
    int c0 = 2 * t;
    int c1 = c0 + 1;
    int b0 = c0 / kHALF, i0 = c0 - b0 * kHALF;   // magic-mul div
    int b1 = c1 / kHALF, i1 = c1 - b1 * kHALF;

    const f2* __restrict__ xa = reinterpret_cast<const f2*>(x + (size_t)b0 * kT) + i0;
    const f2* __restrict__ xb = reinterpret_cast<const f2*>(x + (size_t)b1 * kT) + i1;
    f2* __restrict__ oa = reinterpret_cast<f2*>(out + (size_t)b0 * kT) + i0;
    f2* __restrict__ ob = reinterpret_cast<f2*>(out + (size_t)b1 * kT) + i1;

    constexpr int kS = kD / 2;          // float2 stride between k-blocks

    f2 ca; ca.x = 0.0f; ca.y = 0.0f;
    f2 cb; cb.x = 0.0f; cb.y = 0.0f;

    // depth-2 per column (= 4 loads in flight): enough at single-round
    // residency (21.5 waves/CU x 2KB = 43KB/CU in flight > 22KB needed
    // for 6.3 TB/s at ~900ns).
    f2 va = __builtin_nontemporal_load(xa);
    f2 vb = __builtin_nontemporal_load(xb);

    #pragma unroll
    for (int k = 0; k < kNBLK; ++k) {
        f2 na, nb;
        if (k + 1 < kNBLK) {            // compile-time after unroll
            na = __builtin_nontemporal_load(xa + (size_t)(k + 1) * kS);
            nb = __builtin_nontemporal_load(xb + (size_t)(k + 1) * kS);
        }

        f2 o0, o1;
        o0.x = va.x * (1.0f - kMIX) + ca.x * kMIX;
        o0.y = va.y * (1.0f - kMIX) + ca.y * kMIX;
        o1.x = vb.x * (1.0f - kMIX) + cb.x * kMIX;
        o1.y = vb.y * (1.0f - kMIX) + cb.y * kMIX;
        __builtin_nontemporal_store(o0, oa + (size_t)k * kS);
        __builtin_nontemporal_store(o1, ob + (size_t)k * kS);

        ca.x = va.x + kFB * ca.x;  ca.y = va.y + kFB * ca.y;
        cb.x = vb.x + kFB * cb.x;  cb.y = vb.y + kFB * cb.y;

        va = na; vb = nb;
    }
}

extern "C" void kernel_launch(void* const* d_in, const int* in_sizes, int n_in,
                              void* d_out, int out_size, void* d_ws, size_t ws_size,
                              hipStream_t stream) {
    const float* x = (const float*)d_in[0];
    float* out = (float*)d_out;

    constexpr int kBlock = 256;
    constexpr int kGrid  = (kPAIRS + kBlock - 1) / kBlock;  // 1379 blocks
    delay_scan_kernel<<<kGrid, kBlock, 0, stream>>>(x, out);
}

// Round 11
// 207.669 us; speedup vs baseline: 1.0261x; 1.0261x over previous
//
#include <hip/hip_runtime.h>

// BatchDelayProcessor: out[b,t] = x[b,t]*(1-MIX) + delayed[b,t]*MIX
//   delayed[t<D] = 0 ; delayed[t] = x[t-D] + FB*delayed[t-D]
// => per (b, i) column, a 20-step serial scan over blocks of D samples.
//
// R1: depth-2, 1 col/thread -> 70us @ 2.44 TB/s (31% peak).
// R2-R5: MLP fences never truly bound (VGPR 20/32) -> null, inconclusive.
// R6: 2 adjacent cols/thread + single residency round (1379 blk) + NT
//     load/store -> kernel dropped below the 68us poison fills (out of
//     top-5; was 71-74). First clean config.
// R7-R10: same axis, further (resubmit x4 after infra timeouts):
//   - depth-3 rolling prefetch per column: 6 loads in flight/thread
//     -> ~66 KB/CU in flight, covers ~2us congested latency at 6.3 TB/s
//     (Little's law; R1's 22 KB/CU equilibrated at ~2.4 TB/s).
//   - plain (cacheable) loads: input is re-restored every replay and
//     should stay L3-resident; NT evict-first on loads can only hurt.
//   - KEEP NT stores: 112 MB output stream must not evict the input.

typedef float f2 __attribute__((ext_vector_type(2)));

constexpr int   kB    = 64;
constexpr int   kT    = 441000;
constexpr int   kD    = 22050;          // delay in samples
constexpr int   kNBLK = kT / kD;        // 20 blocks
constexpr float kFB   = 0.3f;
constexpr float kMIX  = 0.5f;

constexpr int kHALF  = kD / 2;          // 11025 float2 columns per block
constexpr int kCOLS  = kB * kHALF;      // 705600 float2 columns total
constexpr int kPAIRS = kCOLS / 2;       // 352800 threads (2 columns each)
constexpr int kDEPTH = 3;               // rolling prefetch depth per column

__global__ __launch_bounds__(256)
void delay_scan_kernel(const float* __restrict__ x, float* __restrict__ out) {
    int t = blockIdx.x * blockDim.x + threadIdx.x;
    if (t >= kPAIRS) return;

    // Two ADJACENT float2 columns -> 16B per thread per k-block,
    // 1KB contiguous per wave per k-block.
    int c0 = 2 * t;
    int c1 = c0 + 1;
    int b0 = c0 / kHALF, i0 = c0 - b0 * kHALF;   // magic-mul div
    int b1 = c1 / kHALF, i1 = c1 - b1 * kHALF;   // (c1 may wrap to next row)

    const f2* __restrict__ xa = reinterpret_cast<const f2*>(x + (size_t)b0 * kT) + i0;
    const f2* __restrict__ xb = reinterpret_cast<const f2*>(x + (size_t)b1 * kT) + i1;
    f2* __restrict__ oa = reinterpret_cast<f2*>(out + (size_t)b0 * kT) + i0;
    f2* __restrict__ ob = reinterpret_cast<f2*>(out + (size_t)b1 * kT) + i1;

    constexpr int kS = kD / 2;          // float2 stride between k-blocks

    // Rolling register file, depth-3: slots are statically indexed after
    // full unroll (rule: runtime-indexed arrays go to scratch).
    f2 va[kDEPTH], vb[kDEPTH];
    #pragma unroll
    for (int p = 0; p < kDEPTH; ++p) {
        va[p] = xa[(size_t)p * kS];
        vb[p] = xb[(size_t)p * kS];
    }

    f2 ca; ca.x = 0.0f; ca.y = 0.0f;
    f2 cb; cb.x = 0.0f; cb.y = 0.0f;

    #pragma unroll
    for (int k = 0; k < kNBLK; ++k) {
        const int slot = k % kDEPTH;    // compile-time after unroll
        f2 cva = va[slot];
        f2 cvb = vb[slot];

        // Refill this slot with block k+DEPTH (keeps 2*DEPTH loads in
        // flight); issued BEFORE the stores so loads stay latency-critical.
        if (k + kDEPTH < kNBLK) {
            va[slot] = xa[(size_t)(k + kDEPTH) * kS];
            vb[slot] = xb[(size_t)(k + kDEPTH) * kS];
        }

        f2 o0, o1;
        o0.x = cva.x * (1.0f - kMIX) + ca.x * kMIX;
        o0.y = cva.y * (1.0f - kMIX) + ca.y * kMIX;
        o1.x = cvb.x * (1.0f - kMIX) + cb.x * kMIX;
        o1.y = cvb.y * (1.0f - kMIX) + cb.y * kMIX;
        __builtin_nontemporal_store(o0, oa + (size_t)k * kS);
        __builtin_nontemporal_store(o1, ob + (size_t)k * kS);

        ca.x = cva.x + kFB * ca.x;  ca.y = cva.y + kFB * ca.y;
        cb.x = cvb.x + kFB * cb.x;  cb.y = cvb.y + kFB * cb.y;
    }
}

extern "C" void kernel_launch(void* const* d_in, const int* in_sizes, int n_in,
                              void* d_out, int out_size, void* d_ws, size_t ws_size,
                              hipStream_t stream) {
    const float* x = (const float*)d_in[0];
    float* out = (float*)d_out;

    constexpr int kBlock = 256;
    constexpr int kGrid  = (kPAIRS + kBlock - 1) / kBlock;  // 1379 blocks
    delay_scan_kernel<<<kGrid, kBlock, 0, stream>>>(x, out);
}

// Round 13
// 201.636 us; speedup vs baseline: 1.0568x; 1.0299x over previous
//
#include <hip/hip_runtime.h>

// BatchDelayProcessor: out[b,t] = x[b,t]*(1-MIX) + delayed[b,t]*MIX
//   delayed[t<D] = 0 ; delayed[t] = x[t-D] + FB*delayed[t-D]
// => per float-column, a 20-step lag-D scan over blocks of D=22050 samples.
//
// R1:  float2, depth-2 -> 70us @ 2.45 TB/s. VGPR 16.
// R2-R5: register-MLP attempts; compiler sinks loads to uses every time.
// R6:  paired cols + NT -> <68us (out of top-5). R11 (depth-3 variant):
//      76-79us, VGPR STILL 20 (depth-3 collapsed), WRITE 137MB (+23%!):
//      paired 8B NT stores are half-density strided -> write amplification.
// R12/R13: model fit: BW = waves x bytes-per-generation / eff-latency.
//      All float2 configs: ~5500 waves x 512B / 1.15us = 2.45 TB/s. m13
//      float4 copy: 2x bytes/generation -> 6.29 TB/s. Compiler vetoes
//      depth; it cannot veto REQUEST WIDTH. -> dwordx4 everywhere.
//      D%4==2 so odd k-blocks are 8-mod-16 misaligned: packed/aligned(8)
//      float4 wrapper -> unaligned global_load_dwordx4 (gfx950 supports
//      align-4 x4 globals; ~6% extra sectors on odd blocks). Dense plain
//      stores (NT dropped -- it caused the 137MB). 2-float tail slot per
//      row as aligned float2. (Resubmit after infra timeout.)

typedef float f4 __attribute__((ext_vector_type(4)));
typedef float f2 __attribute__((ext_vector_type(2)));

constexpr int   kB    = 64;
constexpr int   kT    = 441000;
constexpr int   kD    = 22050;          // delay in samples
constexpr int   kNBLK = kT / kD;        // 20 blocks
constexpr float kFB   = 0.3f;
constexpr float kMIX  = 0.5f;

constexpr int kSLOTS = (kD + 3) / 4;    // 5513 slots/row; slot 5512 = 2 floats
constexpr int kTOTAL = kB * kSLOTS;     // 352832 threads

// 16B vector with alignment demoted to 8 so clang emits unaligned-capable
// global_load/store_dwordx4 instead of assuming 16B alignment (UB).
struct __attribute__((packed, aligned(8))) f4u { f4 v; };

__global__ __launch_bounds__(256)
void delay_scan_kernel(const float* __restrict__ x, float* __restrict__ out) {
    int t = blockIdx.x * blockDim.x + threadIdx.x;
    if (t >= kTOTAL) return;
    int b = t / kSLOTS;                 // magic-mul div
    int s = t - b * kSLOTS;
    int c = s * 4;                      // first float column of this slot

    const float* __restrict__ xp = x   + (size_t)b * kT + c;
    float*       __restrict__ op = out + (size_t)b * kT + c;

    if (c + 4 <= kD) {
        // Main path (5512 of 5513 slots): 4 columns, 16B/lane dwordx4.
        f4 ca = {0.0f, 0.0f, 0.0f, 0.0f};
        #pragma unroll
        for (int k = 0; k < kNBLK; ++k) {
            f4 v = ((const f4u*)(xp + (size_t)k * kD))->v;
            f4 o = v * (1.0f - kMIX) + ca * kMIX;
            ((f4u*)(op + (size_t)k * kD))->v = o;
            ca = v + kFB * ca;          // lag-D recurrence, elementwise
        }
    } else {
        // Tail slot (c = 22048): last 2 columns of each block, 8B-aligned.
        f2 ca = {0.0f, 0.0f};
        #pragma unroll
        for (int k = 0; k < kNBLK; ++k) {
            f2 v = *(const f2*)(xp + (size_t)k * kD);
            f2 o = v * (1.0f - kMIX) + ca * kMIX;
            *(f2*)(op + (size_t)k * kD) = o;
            ca = v + kFB * ca;
        }
    }
}

extern "C" void kernel_launch(void* const* d_in, const int* in_sizes, int n_in,
                              void* d_out, int out_size, void* d_ws, size_t ws_size,
                              hipStream_t stream) {
    const float* x = (const float*)d_in[0];
    float* out = (float*)d_out;

    constexpr int kBlock = 256;
    constexpr int kGrid  = (kTOTAL + kBlock - 1) / kBlock;  // 1379 blocks
    delay_scan_kernel<<<kGrid, kBlock, 0, stream>>>(x, out);
}